// Round 14
// baseline (165.239 us; speedup 1.0000x reference)
//
#include <hip/hip_runtime.h>
#include <hip/hip_bf16.h>
#include <stdint.h>

#define NSEQ 4096
#define DDIM 512
#define NB   8
#define FN   8192          // FFT length = 2*NSEQ

#define PADI(i) ((i) + ((i) >> 5))

struct __align__(8) cf { float x, y; };

__device__ __forceinline__ cf cadd(cf a, cf b) { return {a.x + b.x, a.y + b.y}; }
__device__ __forceinline__ cf csub(cf a, cf b) { return {a.x - b.x, a.y - b.y}; }
__device__ __forceinline__ cf cmul(cf a, cf b) {
    return {a.x * b.x - a.y * b.y, a.x * b.y + a.y * b.x};
}
template<int DIR> __device__ __forceinline__ cf crot(cf z) {  // *(-i) fwd, *(+i) inv
    return DIR < 0 ? cf{z.y, -z.x} : cf{-z.y, z.x};
}

__device__ __forceinline__ unsigned short f2bf(float f) {
    union { float f; unsigned int u; } v;
    v.f = f;
    unsigned int u = v.u;
    u += 0x7FFFu + ((u >> 16) & 1u);   // RNE
    return (unsigned short)(u >> 16);
}
__device__ __forceinline__ float bf2f(unsigned short u) {
    union { unsigned int i; float f; } v;
    v.i = (unsigned int)u << 16;
    return v.f;
}

// ---------------------------------------------------------------------------
// 8-point DFT pieces
// ---------------------------------------------------------------------------
template<int DIR>
__device__ __forceinline__ void fft4(cf& b0, cf& b1, cf& b2, cf& b3) {
    cf s0 = cadd(b0, b2), s1 = csub(b0, b2);
    cf s2 = cadd(b1, b3), s3 = crot<DIR>(csub(b1, b3));
    b0 = cadd(s0, s2); b1 = cadd(s1, s3);
    b2 = csub(s0, s2); b3 = csub(s1, s3);
}

template<int DIR>
__device__ __forceinline__ void dft8(cf a[8]) {
    cf e0 = a[0], e1 = a[2], e2 = a[4], e3 = a[6];
    cf o0 = a[1], o1 = a[3], o2 = a[5], o3 = a[7];
    fft4<DIR>(e0, e1, e2, e3);
    fft4<DIR>(o0, o1, o2, o3);
    const float c = 0.70710678118654752f;
    cf w1 = (DIR < 0) ? cf{c, -c} : cf{c, c};
    cf w3 = (DIR < 0) ? cf{-c, -c} : cf{-c, c};
    o1 = cmul(o1, w1);
    o2 = crot<DIR>(o2);
    o3 = cmul(o3, w3);
    a[0] = cadd(e0, o0); a[1] = cadd(e1, o1); a[2] = cadd(e2, o2); a[3] = cadd(e3, o3);
    a[4] = csub(e0, o0); a[5] = csub(e1, o1); a[6] = csub(e2, o2); a[7] = csub(e3, o3);
}

// DFT8 with a[4..7] == 0 (zero-padded upper half), inputs a0..a3
template<int DIR>
__device__ __forceinline__ void dft8_half(cf a0, cf a1, cf a2, cf a3, cf a[8]) {
    cf r2 = crot<DIR>(a2), r3 = crot<DIR>(a3);
    cf e0 = cadd(a0, a2), e1 = cadd(a0, r2), e2 = csub(a0, a2), e3 = csub(a0, r2);
    cf o0 = cadd(a1, a3), o1 = cadd(a1, r3), o2 = csub(a1, a3), o3 = csub(a1, r3);
    const float c = 0.70710678118654752f;
    cf w1 = (DIR < 0) ? cf{c, -c} : cf{c, c};
    cf w3 = (DIR < 0) ? cf{-c, -c} : cf{-c, c};
    o1 = cmul(o1, w1);
    o2 = crot<DIR>(o2);
    o3 = cmul(o3, w3);
    a[0] = cadd(e0, o0); a[1] = cadd(e1, o1); a[2] = cadd(e2, o2); a[3] = cadd(e3, o3);
    a[4] = csub(e0, o0); a[5] = csub(e1, o1); a[6] = csub(e2, o2); a[7] = csub(e3, o3);
}

// depth-3 twiddle powers w[k] = w1^k, k=1..7
__device__ __forceinline__ void twpow(cf w1, cf w[8]) {
    w[1] = w1;
    w[2] = cmul(w1, w1);
    w[3] = cmul(w[2], w1);
    w[4] = cmul(w[2], w[2]);
    w[5] = cmul(w[4], w1);
    w[6] = cmul(w[4], w[2]);
    w[7] = cmul(w[4], w[3]);
}

// ---------------------------------------------------------------------------
// radix-8 stage over LDS using the LDS twiddle table Wt[t]=e^{-2pi i t/8192}.
// ---------------------------------------------------------------------------
template<int DIR, int NTHR, int LM>
__device__ __forceinline__ void r8_stage_t(cf* Z, const cf* Wt, int tid) {
    const int m = 1 << LM;
#pragma unroll
    for (int q = 0; q < 1024 / NTHR; ++q) {
        int beta = q * NTHR + tid;
        int j = beta & (m - 1);
        int g = beta >> LM;
        int base = (g << (LM + 3)) + j;
        cf a[8];
#pragma unroll
        for (int r = 0; r < 8; ++r) a[r] = Z[PADI(base + (r << LM))];
        cf w1 = Wt[j << (10 - LM)];
        if (DIR > 0) w1.y = -w1.y;
        cf w[8];
        twpow(w1, w);
        if (DIR > 0) {
#pragma unroll
            for (int k = 1; k < 8; ++k) a[k] = cmul(a[k], w[k]);
        }
        dft8<DIR>(a);
        if (DIR < 0) {
#pragma unroll
            for (int k = 1; k < 8; ++k) a[k] = cmul(a[k], w[k]);
        }
#pragma unroll
        for (int r = 0; r < 8; ++r) Z[PADI(base + (r << LM))] = a[r];
    }
}

// radix-2 stage on adjacent pairs (used only in build_V's full chain)
template<int NTHR>
__device__ __forceinline__ void r2_stage(cf* Z, int tid) {
#pragma unroll
    for (int q = 0; q < 4096 / NTHR; ++q) {
        int beta = q * NTHR + tid;
        int i0 = PADI(2 * beta), i1 = i0 + 1;
        cf a = Z[i0], b = Z[i1];
        Z[i0] = cadd(a, b);
        Z[i1] = csub(a, b);
    }
}

// sincos-based radix-8 stage (build_V only; runs once)
template<int DIR, int NTHR>
__device__ __forceinline__ void r8_stage(cf* Z, int lm, int tid) {
    const int m = 1 << lm;
    const float ang0 = ((DIR < 0) ? -6.2831853071795865f : 6.2831853071795865f)
                       / (float)(m * 8);
#pragma unroll
    for (int q = 0; q < 1024 / NTHR; ++q) {
        int beta = q * NTHR + tid;
        int j = beta & (m - 1);
        int g = beta >> lm;
        int base = (g << (lm + 3)) + j;
        cf a[8];
#pragma unroll
        for (int r = 0; r < 8; ++r) a[r] = Z[PADI(base + (r << lm))];
        float sn, cs;
        __sincosf(ang0 * (float)j, &sn, &cs);
        cf w[8];
        twpow({cs, sn}, w);
        if (DIR > 0) {
#pragma unroll
            for (int k = 1; k < 8; ++k) a[k] = cmul(a[k], w[k]);
        }
        dft8<DIR>(a);
        if (DIR < 0) {
#pragma unroll
            for (int k = 1; k < 8; ++k) a[k] = cmul(a[k], w[k]);
        }
#pragma unroll
        for (int r = 0; r < 8; ++r) Z[PADI(base + (r << lm))] = a[r];
    }
}

// ---------------------------------------------------------------------------
// Kernel 1: transpose+convert  xT[b][d][j] = bf16(x[b][j][d]).  4096 blocks.
// ---------------------------------------------------------------------------
__global__ void transpose_x(const float* __restrict__ x,
                            unsigned short* __restrict__ xT) {
    __shared__ unsigned short tl[64][72];
    int t   = blockIdx.x;
    int b   = t >> 9;
    int rem = t & 511;
    int j0  = (rem >> 3) << 6;
    int d0  = (rem & 7) << 6;
    const float* xb = x + (size_t)b * NSEQ * DDIM;
#pragma unroll
    for (int e = 0; e < 4; ++e) {
        int idx = e * 256 + threadIdx.x;
        int r   = idx >> 4;
        int c4  = (idx & 15) << 2;
        float4 v = *(const float4*)&xb[(size_t)(j0 + r) * DDIM + d0 + c4];
        ushort4 o;
        o.x = f2bf(v.x); o.y = f2bf(v.y); o.z = f2bf(v.z); o.w = f2bf(v.w);
        *(ushort4*)&tl[r][c4] = o;
    }
    __syncthreads();
    unsigned short* xtb = xT + (size_t)b * DDIM * NSEQ;
#pragma unroll
    for (int e = 0; e < 4; ++e) {
        int idx = e * 256 + threadIdx.x;
        int d   = idx >> 4;
        int jq  = (idx & 15) << 2;
        ushort4 o;
        o.x = tl[jq + 0][d]; o.y = tl[jq + 1][d];
        o.z = tl[jq + 2][d]; o.w = tl[jq + 3][d];
        *(ushort4*)&xtb[(size_t)(d0 + d) * NSEQ + j0 + jq] = o;
    }
}

// ---------------------------------------------------------------------------
// Kernel 2: build V-hat = full DIF-FFT (incl. r2) of exp(clamp(kernel)),
// digit-reversed order, pre-scaled by 1/8192.  ONE block, 512 threads.
// ---------------------------------------------------------------------------
__global__ __launch_bounds__(512) void build_V(const float* __restrict__ pos,
                                               const float* __restrict__ zero,
                                               const float* __restrict__ neg,
                                               cf* __restrict__ Vh) {
    __shared__ cf Z[PADI(FN)];
    int tid = threadIdx.x;
    float zv = zero[0];
#pragma unroll
    for (int q = 0; q < 16; ++q) {
        int t = q * 512 + tid;
        float v;
        if (t == 0 || t == NSEQ) v = zv;
        else if (t < NSEQ)       v = pos[t - 1];
        else                     v = neg[t - NSEQ - 1];
        v = fminf(fmaxf(v, -60.0f), 30.0f);
        Z[PADI(t)] = {__expf(v), 0.0f};
    }
    __syncthreads();
    r8_stage<-1, 512>(Z, 10, tid); __syncthreads();
    r8_stage<-1, 512>(Z, 7,  tid); __syncthreads();
    r8_stage<-1, 512>(Z, 4,  tid); __syncthreads();
    r8_stage<-1, 512>(Z, 1,  tid); __syncthreads();
    r2_stage<512>(Z, tid);         __syncthreads();
    const float sc = 1.0f / (float)FN;
#pragma unroll
    for (int q = 0; q < 16; ++q) {
        int i = q * 512 + tid;
        cf v = Z[PADI(i)];
        Vh[i] = {v.x * sc, v.y * sc};
    }
}

// ---------------------------------------------------------------------------
// Kernel 3: per column-pair FFT convolution, 1024 threads, 2 blocks/CU.
// LDS twiddle table (no sincos in stages).  First fwd / last inv stages fused
// with global load/store.  Middle: fwd-lm1 + R2 diag(Vh) R2 + inv-lm1 merged
// into ONE register pass with shfl_xor pairing and constant lm1 twiddles.
// ---------------------------------------------------------------------------
__global__ __launch_bounds__(1024, 8) void fft_conv(unsigned short* __restrict__ xT,
                                                    const cf* __restrict__ Vh) {
    __shared__ cf Z[PADI(FN)];
    __shared__ cf Wt[1024];
    int tid = threadIdx.x;
    int blk = blockIdx.x;
    int b   = blk >> 8;
    int dp  = blk & 255;
    unsigned short* col0 = xT + ((size_t)(b * DDIM + 2 * dp)) * NSEQ;
    unsigned short* col1 = col0 + NSEQ;

    // ---- build twiddle table: Wt[t] = e^{-2pi i t / 8192} ----
    {
        float sn, cs;
        __sincosf(-7.66990393942820625e-04f * (float)tid, &sn, &cs);
        Wt[tid] = {cs, sn};
    }

    // global loads issued before the table barrier; consumed after
    cf a0 = {bf2f(col0[tid]),        bf2f(col1[tid])};
    cf a1 = {bf2f(col0[tid + 1024]), bf2f(col1[tid + 1024])};
    cf a2 = {bf2f(col0[tid + 2048]), bf2f(col1[tid + 2048])};
    cf a3 = {bf2f(col0[tid + 3072]), bf2f(col1[tid + 3072])};
    __syncthreads();

    // ---- fused first forward stage (lm=10, half-zero), table twiddle ----
    {
        cf a[8];
        dft8_half<-1>(a0, a1, a2, a3, a);
        cf w[8];
        twpow(Wt[tid], w);
#pragma unroll
        for (int k = 1; k < 8; ++k) a[k] = cmul(a[k], w[k]);
#pragma unroll
        for (int r = 0; r < 8; ++r) Z[PADI(tid + (r << 10))] = a[r];
    }
    __syncthreads();

    r8_stage_t<-1, 1024, 7>(Z, Wt, tid);  __syncthreads();
    r8_stage_t<-1, 1024, 4>(Z, Wt, tid);  __syncthreads();

    // ---- merged: fwd lm=1 + R2 diag(Vh) R2 + inv lm=1, in registers ----
    {
        const int g  = tid >> 1;      // group 0..511
        const int jj = tid & 1;
        const int base = g * 16 + jj;
        cf a[8];
#pragma unroll
        for (int r = 0; r < 8; ++r) a[r] = Z[PADI(base + 2 * r)];
        dft8<-1>(a);
        // lm=1 fwd twiddles: w1 = e^{-i pi/8} (j=1 only), compile-time consts
        const float C1 = 0.92387953251128674f, S1 = 0.38268343236508977f;
        const float C2 = 0.70710678118654752f;
        if (jj) {
            a[1] = cmul(a[1], {C1, -S1});
            a[2] = cmul(a[2], {C2, -C2});
            a[3] = cmul(a[3], {S1, -C1});
            a[4] = crot<-1>(a[4]);
            a[5] = cmul(a[5], {-S1, -C1});
            a[6] = cmul(a[6], {-C2, -C2});
            a[7] = cmul(a[7], {-C1, -S1});
        }
        // pair (2p,2p+1) = (even-thread a[r], odd-thread a[r]), p = g*8+r
        const float4* V4 = (const float4*)Vh;
#pragma unroll
        for (int r = 0; r < 8; ++r) {
            cf own = a[r];
            cf oth;
            oth.x = __shfl_xor(own.x, 1);
            oth.y = __shfl_xor(own.y, 1);
            float4 v = V4[g * 8 + r];
            cf V0 = {v.x, v.y}, V1 = {v.z, v.w};
            cf Vp = cadd(V0, V1), Vm = csub(V0, V1);
            a[r] = cadd(cmul(Vp, own), cmul(Vm, oth));
        }
        // inv lm=1: twiddle first (conjugates), then dft8<+1>
        if (jj) {
            a[1] = cmul(a[1], {C1, S1});
            a[2] = cmul(a[2], {C2, C2});
            a[3] = cmul(a[3], {S1, C1});
            a[4] = crot<1>(a[4]);
            a[5] = cmul(a[5], {-S1, C1});
            a[6] = cmul(a[6], {-C2, C2});
            a[7] = cmul(a[7], {-C1, S1});
        }
        dft8<1>(a);
#pragma unroll
        for (int r = 0; r < 8; ++r) Z[PADI(base + 2 * r)] = a[r];
    }
    __syncthreads();

    r8_stage_t<1, 1024, 4>(Z, Wt, tid);   __syncthreads();
    r8_stage_t<1, 1024, 7>(Z, Wt, tid);   __syncthreads();

    // ---- fused last inverse stage (lm=10) + store (only idx < 4096) ----
    {
        cf a[8];
#pragma unroll
        for (int r = 0; r < 8; ++r) a[r] = Z[PADI(tid + (r << 10))];
        cf w1 = Wt[tid];
        w1.y = -w1.y;
        cf w[8];
        twpow(w1, w);
#pragma unroll
        for (int k = 1; k < 8; ++k) a[k] = cmul(a[k], w[k]);
        dft8<1>(a);
#pragma unroll
        for (int r = 0; r < 4; ++r) {
            col0[tid + (r << 10)] = f2bf(a[r].x);
            col1[tid + (r << 10)] = f2bf(a[r].y);
        }
    }
}

// ---------------------------------------------------------------------------
// Kernel 4: un-transpose  out[b][j][d] = f32(outT[b][d][j]).  grid (64,8,8).
// ---------------------------------------------------------------------------
__global__ void untranspose(const unsigned short* __restrict__ oT,
                            float* __restrict__ out) {
    __shared__ unsigned short tl[64][65];
    int j0 = blockIdx.x * 64, d0 = blockIdx.y * 64, b = blockIdx.z;
    const unsigned short* src = oT + (size_t)b * DDIM * NSEQ;
#pragma unroll
    for (int e = 0; e < 16; ++e) {
        int idx = e * 256 + threadIdx.x;
        int r = idx >> 6, c = idx & 63;
        tl[r][c] = src[(size_t)(d0 + r) * NSEQ + j0 + c];
    }
    __syncthreads();
    float* dst = out + ((size_t)b * NSEQ + j0) * DDIM + d0;
#pragma unroll
    for (int e = 0; e < 16; ++e) {
        int idx = e * 256 + threadIdx.x;
        int r = idx >> 6, c = idx & 63;
        dst[(size_t)r * DDIM + c] = bf2f(tl[c][r]);
    }
}

// ---------------------------------------------------------------------------
extern "C" void kernel_launch(void* const* d_in, const int* in_sizes, int n_in,
                              void* d_out, int out_size, void* d_ws, size_t ws_size,
                              hipStream_t stream) {
    const float* x    = (const float*)d_in[0];
    const float* pos  = (const float*)d_in[1];
    const float* zero = (const float*)d_in[2];
    const float* neg  = (const float*)d_in[3];
    float* out = (float*)d_out;

    unsigned short* xT = (unsigned short*)d_ws;                       // 32 MiB
    cf* Vh = (cf*)((char*)d_ws + (size_t)32 * 1024 * 1024);           // 64 KiB

    build_V<<<dim3(1), 512, 0, stream>>>(pos, zero, neg, Vh);
    transpose_x<<<dim3(4096), 256, 0, stream>>>(x, xT);
    fft_conv<<<dim3(NB * 256), 1024, 0, stream>>>(xT, Vh);
    untranspose<<<dim3(64, 8, 8), 256, 0, stream>>>(xT, out);
}

// Round 15
// 116.612 us; speedup vs baseline: 1.4170x; 1.4170x over previous
//
#include <hip/hip_runtime.h>
#include <hip/hip_bf16.h>
#include <stdint.h>

#define NSEQ 4096
#define DDIM 512
#define NB   8
#define FN   8192          // FFT length = 2*NSEQ

#define PADI(i) ((i) + ((i) >> 5))

struct __align__(8) cf { float x, y; };

__device__ __forceinline__ cf cadd(cf a, cf b) { return {a.x + b.x, a.y + b.y}; }
__device__ __forceinline__ cf csub(cf a, cf b) { return {a.x - b.x, a.y - b.y}; }
__device__ __forceinline__ cf cmul(cf a, cf b) {
    return {a.x * b.x - a.y * b.y, a.x * b.y + a.y * b.x};
}
template<int DIR> __device__ __forceinline__ cf crot(cf z) {  // *(-i) fwd, *(+i) inv
    return DIR < 0 ? cf{z.y, -z.x} : cf{-z.y, z.x};
}

__device__ __forceinline__ unsigned short f2bf(float f) {
    union { float f; unsigned int u; } v;
    v.f = f;
    unsigned int u = v.u;
    u += 0x7FFFu + ((u >> 16) & 1u);   // RNE
    return (unsigned short)(u >> 16);
}
__device__ __forceinline__ float bf2f(unsigned short u) {
    union { unsigned int i; float f; } v;
    v.i = (unsigned int)u << 16;
    return v.f;
}

// ---------------------------------------------------------------------------
// 8-point DFT pieces
// ---------------------------------------------------------------------------
template<int DIR>
__device__ __forceinline__ void fft4(cf& b0, cf& b1, cf& b2, cf& b3) {
    cf s0 = cadd(b0, b2), s1 = csub(b0, b2);
    cf s2 = cadd(b1, b3), s3 = crot<DIR>(csub(b1, b3));
    b0 = cadd(s0, s2); b1 = cadd(s1, s3);
    b2 = csub(s0, s2); b3 = csub(s1, s3);
}

template<int DIR>
__device__ __forceinline__ void dft8(cf a[8]) {
    cf e0 = a[0], e1 = a[2], e2 = a[4], e3 = a[6];
    cf o0 = a[1], o1 = a[3], o2 = a[5], o3 = a[7];
    fft4<DIR>(e0, e1, e2, e3);
    fft4<DIR>(o0, o1, o2, o3);
    const float c = 0.70710678118654752f;
    cf w1 = (DIR < 0) ? cf{c, -c} : cf{c, c};
    cf w3 = (DIR < 0) ? cf{-c, -c} : cf{-c, c};
    o1 = cmul(o1, w1);
    o2 = crot<DIR>(o2);
    o3 = cmul(o3, w3);
    a[0] = cadd(e0, o0); a[1] = cadd(e1, o1); a[2] = cadd(e2, o2); a[3] = cadd(e3, o3);
    a[4] = csub(e0, o0); a[5] = csub(e1, o1); a[6] = csub(e2, o2); a[7] = csub(e3, o3);
}

// DFT8 with a[4..7] == 0 (zero-padded upper half), inputs a0..a3
template<int DIR>
__device__ __forceinline__ void dft8_half(cf a0, cf a1, cf a2, cf a3, cf a[8]) {
    cf r2 = crot<DIR>(a2), r3 = crot<DIR>(a3);
    cf e0 = cadd(a0, a2), e1 = cadd(a0, r2), e2 = csub(a0, a2), e3 = csub(a0, r2);
    cf o0 = cadd(a1, a3), o1 = cadd(a1, r3), o2 = csub(a1, a3), o3 = csub(a1, r3);
    const float c = 0.70710678118654752f;
    cf w1 = (DIR < 0) ? cf{c, -c} : cf{c, c};
    cf w3 = (DIR < 0) ? cf{-c, -c} : cf{-c, c};
    o1 = cmul(o1, w1);
    o2 = crot<DIR>(o2);
    o3 = cmul(o3, w3);
    a[0] = cadd(e0, o0); a[1] = cadd(e1, o1); a[2] = cadd(e2, o2); a[3] = cadd(e3, o3);
    a[4] = csub(e0, o0); a[5] = csub(e1, o1); a[6] = csub(e2, o2); a[7] = csub(e3, o3);
}

// depth-3 twiddle powers w[k] = w1^k, k=1..7
__device__ __forceinline__ void twpow(cf w1, cf w[8]) {
    w[1] = w1;
    w[2] = cmul(w1, w1);
    w[3] = cmul(w[2], w1);
    w[4] = cmul(w[2], w[2]);
    w[5] = cmul(w[4], w1);
    w[6] = cmul(w[4], w[2]);
    w[7] = cmul(w[4], w[3]);
}

// ---------------------------------------------------------------------------
// radix-8 stage over LDS using the LDS twiddle table Wt[t]=e^{-2pi i t/8192}.
// ---------------------------------------------------------------------------
template<int DIR, int NTHR, int LM>
__device__ __forceinline__ void r8_stage_t(cf* Z, const cf* Wt, int tid) {
    const int m = 1 << LM;
#pragma unroll
    for (int q = 0; q < 1024 / NTHR; ++q) {
        int beta = q * NTHR + tid;
        int j = beta & (m - 1);
        int g = beta >> LM;
        int base = (g << (LM + 3)) + j;
        cf a[8];
#pragma unroll
        for (int r = 0; r < 8; ++r) a[r] = Z[PADI(base + (r << LM))];
        cf w1 = Wt[j << (10 - LM)];
        if (DIR > 0) w1.y = -w1.y;
        cf w[8];
        twpow(w1, w);
        if (DIR > 0) {
#pragma unroll
            for (int k = 1; k < 8; ++k) a[k] = cmul(a[k], w[k]);
        }
        dft8<DIR>(a);
        if (DIR < 0) {
#pragma unroll
            for (int k = 1; k < 8; ++k) a[k] = cmul(a[k], w[k]);
        }
#pragma unroll
        for (int r = 0; r < 8; ++r) Z[PADI(base + (r << LM))] = a[r];
    }
}

// radix-2 stage on adjacent pairs (used only in build_V's full chain)
template<int NTHR>
__device__ __forceinline__ void r2_stage(cf* Z, int tid) {
#pragma unroll
    for (int q = 0; q < 4096 / NTHR; ++q) {
        int beta = q * NTHR + tid;
        int i0 = PADI(2 * beta), i1 = i0 + 1;
        cf a = Z[i0], b = Z[i1];
        Z[i0] = cadd(a, b);
        Z[i1] = csub(a, b);
    }
}

// sincos-based radix-8 stage (build_V only; runs once)
template<int DIR, int NTHR>
__device__ __forceinline__ void r8_stage(cf* Z, int lm, int tid) {
    const int m = 1 << lm;
    const float ang0 = ((DIR < 0) ? -6.2831853071795865f : 6.2831853071795865f)
                       / (float)(m * 8);
#pragma unroll
    for (int q = 0; q < 1024 / NTHR; ++q) {
        int beta = q * NTHR + tid;
        int j = beta & (m - 1);
        int g = beta >> lm;
        int base = (g << (lm + 3)) + j;
        cf a[8];
#pragma unroll
        for (int r = 0; r < 8; ++r) a[r] = Z[PADI(base + (r << lm))];
        float sn, cs;
        __sincosf(ang0 * (float)j, &sn, &cs);
        cf w[8];
        twpow({cs, sn}, w);
        if (DIR > 0) {
#pragma unroll
            for (int k = 1; k < 8; ++k) a[k] = cmul(a[k], w[k]);
        }
        dft8<DIR>(a);
        if (DIR < 0) {
#pragma unroll
            for (int k = 1; k < 8; ++k) a[k] = cmul(a[k], w[k]);
        }
#pragma unroll
        for (int r = 0; r < 8; ++r) Z[PADI(base + (r << lm))] = a[r];
    }
}

// ---------------------------------------------------------------------------
// Kernel 1: transpose+convert  xT[b][d][j] = bf16(x[b][j][d]).  4096 blocks.
// ---------------------------------------------------------------------------
__global__ void transpose_x(const float* __restrict__ x,
                            unsigned short* __restrict__ xT) {
    __shared__ unsigned short tl[64][72];
    int t   = blockIdx.x;
    int b   = t >> 9;
    int rem = t & 511;
    int j0  = (rem >> 3) << 6;
    int d0  = (rem & 7) << 6;
    const float* xb = x + (size_t)b * NSEQ * DDIM;
#pragma unroll
    for (int e = 0; e < 4; ++e) {
        int idx = e * 256 + threadIdx.x;
        int r   = idx >> 4;
        int c4  = (idx & 15) << 2;
        float4 v = *(const float4*)&xb[(size_t)(j0 + r) * DDIM + d0 + c4];
        ushort4 o;
        o.x = f2bf(v.x); o.y = f2bf(v.y); o.z = f2bf(v.z); o.w = f2bf(v.w);
        *(ushort4*)&tl[r][c4] = o;
    }
    __syncthreads();
    unsigned short* xtb = xT + (size_t)b * DDIM * NSEQ;
#pragma unroll
    for (int e = 0; e < 4; ++e) {
        int idx = e * 256 + threadIdx.x;
        int d   = idx >> 4;
        int jq  = (idx & 15) << 2;
        ushort4 o;
        o.x = tl[jq + 0][d]; o.y = tl[jq + 1][d];
        o.z = tl[jq + 2][d]; o.w = tl[jq + 3][d];
        *(ushort4*)&xtb[(size_t)(d0 + d) * NSEQ + j0 + jq] = o;
    }
}

// ---------------------------------------------------------------------------
// Kernel 2: build V-hat = full DIF-FFT (incl. r2) of exp(clamp(kernel)),
// digit-reversed order, pre-scaled by 1/8192.  ONE block, 512 threads.
// ---------------------------------------------------------------------------
__global__ __launch_bounds__(512) void build_V(const float* __restrict__ pos,
                                               const float* __restrict__ zero,
                                               const float* __restrict__ neg,
                                               cf* __restrict__ Vh) {
    __shared__ cf Z[PADI(FN)];
    int tid = threadIdx.x;
    float zv = zero[0];
#pragma unroll
    for (int q = 0; q < 16; ++q) {
        int t = q * 512 + tid;
        float v;
        if (t == 0 || t == NSEQ) v = zv;
        else if (t < NSEQ)       v = pos[t - 1];
        else                     v = neg[t - NSEQ - 1];
        v = fminf(fmaxf(v, -60.0f), 30.0f);
        Z[PADI(t)] = {__expf(v), 0.0f};
    }
    __syncthreads();
    r8_stage<-1, 512>(Z, 10, tid); __syncthreads();
    r8_stage<-1, 512>(Z, 7,  tid); __syncthreads();
    r8_stage<-1, 512>(Z, 4,  tid); __syncthreads();
    r8_stage<-1, 512>(Z, 1,  tid); __syncthreads();
    r2_stage<512>(Z, tid);         __syncthreads();
    const float sc = 1.0f / (float)FN;
#pragma unroll
    for (int q = 0; q < 16; ++q) {
        int i = q * 512 + tid;
        cf v = Z[PADI(i)];
        Vh[i] = {v.x * sc, v.y * sc};
    }
}

// ---------------------------------------------------------------------------
// Kernel 3: per column-pair FFT convolution.  512 threads, 2 blocks/CU,
// __launch_bounds__(512,4) -> 128 VGPR cap, NO SPILL (r14 lesson: the 1024,8
// variant spilled ~470 MB scratch/dispatch).  LDS twiddle table; fused
// first/last stages; merged fwd-lm1 + R2 diag(Vh) R2 + inv-lm1 register pass.
// ---------------------------------------------------------------------------
__global__ __launch_bounds__(512, 4) void fft_conv(unsigned short* __restrict__ xT,
                                                   const cf* __restrict__ Vh) {
    __shared__ cf Z[PADI(FN)];
    __shared__ cf Wt[1024];
    int tid = threadIdx.x;
    int blk = blockIdx.x;
    int b   = blk >> 8;
    int dp  = blk & 255;
    unsigned short* col0 = xT + ((size_t)(b * DDIM + 2 * dp)) * NSEQ;
    unsigned short* col1 = col0 + NSEQ;

    // ---- build twiddle table: Wt[t] = e^{-2pi i t / 8192} ----
#pragma unroll
    for (int q = 0; q < 2; ++q) {
        int t = q * 512 + tid;
        float sn, cs;
        __sincosf(-7.66990393942820625e-04f * (float)t, &sn, &cs);
        Wt[t] = {cs, sn};
    }
    __syncthreads();

    // ---- fused load + first forward stage (lm=10, half-zero) ----
#pragma unroll
    for (int q = 0; q < 2; ++q) {
        int j = q * 512 + tid;
        cf a0 = {bf2f(col0[j]),        bf2f(col1[j])};
        cf a1 = {bf2f(col0[j + 1024]), bf2f(col1[j + 1024])};
        cf a2 = {bf2f(col0[j + 2048]), bf2f(col1[j + 2048])};
        cf a3 = {bf2f(col0[j + 3072]), bf2f(col1[j + 3072])};
        cf a[8];
        dft8_half<-1>(a0, a1, a2, a3, a);
        cf w[8];
        twpow(Wt[j], w);
#pragma unroll
        for (int k = 1; k < 8; ++k) a[k] = cmul(a[k], w[k]);
#pragma unroll
        for (int r = 0; r < 8; ++r) Z[PADI(j + (r << 10))] = a[r];
    }
    __syncthreads();

    r8_stage_t<-1, 512, 7>(Z, Wt, tid);  __syncthreads();
    r8_stage_t<-1, 512, 4>(Z, Wt, tid);  __syncthreads();

    // ---- merged: fwd lm=1 + R2 diag(Vh) R2 + inv lm=1, in registers ----
    const float4* V4 = (const float4*)Vh;
#pragma unroll
    for (int q = 0; q < 2; ++q) {
        const int idx = q * 512 + tid;
        const int g  = idx >> 1;      // group 0..511
        const int jj = idx & 1;       // == tid&1 -> lane-adjacent pairing
        const int base = g * 16 + jj;
        cf a[8];
#pragma unroll
        for (int r = 0; r < 8; ++r) a[r] = Z[PADI(base + 2 * r)];
        dft8<-1>(a);
        // lm=1 fwd twiddles: w1 = e^{-i pi k/8} for jj=1, compile-time consts
        const float C1 = 0.92387953251128674f, S1 = 0.38268343236508977f;
        const float C2 = 0.70710678118654752f;
        if (jj) {
            a[1] = cmul(a[1], {C1, -S1});
            a[2] = cmul(a[2], {C2, -C2});
            a[3] = cmul(a[3], {S1, -C1});
            a[4] = crot<-1>(a[4]);
            a[5] = cmul(a[5], {-S1, -C1});
            a[6] = cmul(a[6], {-C2, -C2});
            a[7] = cmul(a[7], {-C1, -S1});
        }
        // pair (2p,2p+1) = (even-lane a[r], odd-lane a[r]), p = g*8+r
#pragma unroll
        for (int r = 0; r < 8; ++r) {
            cf own = a[r];
            cf oth;
            oth.x = __shfl_xor(own.x, 1);
            oth.y = __shfl_xor(own.y, 1);
            float4 v = V4[g * 8 + r];
            cf V0 = {v.x, v.y}, V1 = {v.z, v.w};
            cf Vp = cadd(V0, V1), Vm = csub(V0, V1);
            a[r] = cadd(cmul(Vp, own), cmul(Vm, oth));
        }
        // inv lm=1: twiddle first (conjugates), then dft8<+1>
        if (jj) {
            a[1] = cmul(a[1], {C1, S1});
            a[2] = cmul(a[2], {C2, C2});
            a[3] = cmul(a[3], {S1, C1});
            a[4] = crot<1>(a[4]);
            a[5] = cmul(a[5], {-S1, C1});
            a[6] = cmul(a[6], {-C2, C2});
            a[7] = cmul(a[7], {-C1, S1});
        }
        dft8<1>(a);
#pragma unroll
        for (int r = 0; r < 8; ++r) Z[PADI(base + 2 * r)] = a[r];
    }
    __syncthreads();

    r8_stage_t<1, 512, 4>(Z, Wt, tid);   __syncthreads();
    r8_stage_t<1, 512, 7>(Z, Wt, tid);   __syncthreads();

    // ---- fused last inverse stage (lm=10) + store (only idx < 4096) ----
#pragma unroll
    for (int q = 0; q < 2; ++q) {
        int j = q * 512 + tid;
        cf a[8];
#pragma unroll
        for (int r = 0; r < 8; ++r) a[r] = Z[PADI(j + (r << 10))];
        cf w1 = Wt[j];
        w1.y = -w1.y;
        cf w[8];
        twpow(w1, w);
#pragma unroll
        for (int k = 1; k < 8; ++k) a[k] = cmul(a[k], w[k]);
        dft8<1>(a);
#pragma unroll
        for (int r = 0; r < 4; ++r) {
            col0[j + (r << 10)] = f2bf(a[r].x);
            col1[j + (r << 10)] = f2bf(a[r].y);
        }
    }
}

// ---------------------------------------------------------------------------
// Kernel 4: un-transpose  out[b][j][d] = f32(outT[b][d][j]).  grid (64,8,8).
// ---------------------------------------------------------------------------
__global__ void untranspose(const unsigned short* __restrict__ oT,
                            float* __restrict__ out) {
    __shared__ unsigned short tl[64][65];
    int j0 = blockIdx.x * 64, d0 = blockIdx.y * 64, b = blockIdx.z;
    const unsigned short* src = oT + (size_t)b * DDIM * NSEQ;
#pragma unroll
    for (int e = 0; e < 16; ++e) {
        int idx = e * 256 + threadIdx.x;
        int r = idx >> 6, c = idx & 63;
        tl[r][c] = src[(size_t)(d0 + r) * NSEQ + j0 + c];
    }
    __syncthreads();
    float* dst = out + ((size_t)b * NSEQ + j0) * DDIM + d0;
#pragma unroll
    for (int e = 0; e < 16; ++e) {
        int idx = e * 256 + threadIdx.x;
        int r = idx >> 6, c = idx & 63;
        dst[(size_t)r * DDIM + c] = bf2f(tl[c][r]);
    }
}

// ---------------------------------------------------------------------------
extern "C" void kernel_launch(void* const* d_in, const int* in_sizes, int n_in,
                              void* d_out, int out_size, void* d_ws, size_t ws_size,
                              hipStream_t stream) {
    const float* x    = (const float*)d_in[0];
    const float* pos  = (const float*)d_in[1];
    const float* zero = (const float*)d_in[2];
    const float* neg  = (const float*)d_in[3];
    float* out = (float*)d_out;

    unsigned short* xT = (unsigned short*)d_ws;                       // 32 MiB
    cf* Vh = (cf*)((char*)d_ws + (size_t)32 * 1024 * 1024);           // 64 KiB

    build_V<<<dim3(1), 512, 0, stream>>>(pos, zero, neg, Vh);
    transpose_x<<<dim3(4096), 256, 0, stream>>>(x, xT);
    fft_conv<<<dim3(NB * 256), 512, 0, stream>>>(xT, Vh);
    untranspose<<<dim3(64, 8, 8), 256, 0, stream>>>(xT, out);
}

// Round 16
// 112.340 us; speedup vs baseline: 1.4709x; 1.0380x over previous
//
#include <hip/hip_runtime.h>
#include <hip/hip_bf16.h>
#include <stdint.h>

#define NSEQ 4096
#define DDIM 512
#define NB   8
#define FN   8192          // FFT length = 2*NSEQ

#define PADI(i) ((i) + ((i) >> 5))

// complex as 2xf32 vector -> compiler emits v_pk_add_f32 / v_pk_fma_f32
typedef float cf __attribute__((ext_vector_type(2)));

__device__ __forceinline__ cf cmul(cf a, cf b) {
    cf s = a.yx * b.yy;            // {ay*by, ax*by}   (pk_mul, op_sel swizzle)
    s.x = -s.x;
    return __builtin_elementwise_fma(a, b.xx, s);  // {ax bx - ay by, ay bx + ax by}
}
template<int DIR> __device__ __forceinline__ cf crot(cf z) {  // *(-i) fwd, *(+i) inv
    return DIR < 0 ? (cf){z.y, -z.x} : (cf){-z.y, z.x};
}

__device__ __forceinline__ unsigned short f2bf(float f) {
    union { float f; unsigned int u; } v;
    v.f = f;
    unsigned int u = v.u;
    u += 0x7FFFu + ((u >> 16) & 1u);   // RNE
    return (unsigned short)(u >> 16);
}
__device__ __forceinline__ float bf2f(unsigned short u) {
    union { unsigned int i; float f; } v;
    v.i = (unsigned int)u << 16;
    return v.f;
}

// ---------------------------------------------------------------------------
// 8-point DFT pieces (packed-math complex ops)
// ---------------------------------------------------------------------------
template<int DIR>
__device__ __forceinline__ void fft4(cf& b0, cf& b1, cf& b2, cf& b3) {
    cf s0 = b0 + b2, s1 = b0 - b2;
    cf s2 = b1 + b3, s3 = crot<DIR>(b1 - b3);
    b0 = s0 + s2; b1 = s1 + s3;
    b2 = s0 - s2; b3 = s1 - s3;
}

template<int DIR>
__device__ __forceinline__ void dft8(cf a[8]) {
    cf e0 = a[0], e1 = a[2], e2 = a[4], e3 = a[6];
    cf o0 = a[1], o1 = a[3], o2 = a[5], o3 = a[7];
    fft4<DIR>(e0, e1, e2, e3);
    fft4<DIR>(o0, o1, o2, o3);
    const float c = 0.70710678118654752f;
    cf w1 = (DIR < 0) ? (cf){c, -c} : (cf){c, c};
    cf w3 = (DIR < 0) ? (cf){-c, -c} : (cf){-c, c};
    o1 = cmul(o1, w1);
    o2 = crot<DIR>(o2);
    o3 = cmul(o3, w3);
    a[0] = e0 + o0; a[1] = e1 + o1; a[2] = e2 + o2; a[3] = e3 + o3;
    a[4] = e0 - o0; a[5] = e1 - o1; a[6] = e2 - o2; a[7] = e3 - o3;
}

// DFT8 with a[4..7] == 0 (zero-padded upper half), inputs a0..a3
template<int DIR>
__device__ __forceinline__ void dft8_half(cf a0, cf a1, cf a2, cf a3, cf a[8]) {
    cf r2 = crot<DIR>(a2), r3 = crot<DIR>(a3);
    cf e0 = a0 + a2, e1 = a0 + r2, e2 = a0 - a2, e3 = a0 - r2;
    cf o0 = a1 + a3, o1 = a1 + r3, o2 = a1 - a3, o3 = a1 - r3;
    const float c = 0.70710678118654752f;
    cf w1 = (DIR < 0) ? (cf){c, -c} : (cf){c, c};
    cf w3 = (DIR < 0) ? (cf){-c, -c} : (cf){-c, c};
    o1 = cmul(o1, w1);
    o2 = crot<DIR>(o2);
    o3 = cmul(o3, w3);
    a[0] = e0 + o0; a[1] = e1 + o1; a[2] = e2 + o2; a[3] = e3 + o3;
    a[4] = e0 - o0; a[5] = e1 - o1; a[6] = e2 - o2; a[7] = e3 - o3;
}

// depth-3 twiddle powers w[k] = w1^k, k=1..7
__device__ __forceinline__ void twpow(cf w1, cf w[8]) {
    w[1] = w1;
    w[2] = cmul(w1, w1);
    w[3] = cmul(w[2], w1);
    w[4] = cmul(w[2], w[2]);
    w[5] = cmul(w[4], w1);
    w[6] = cmul(w[4], w[2]);
    w[7] = cmul(w[4], w[3]);
}

// ---------------------------------------------------------------------------
// radix-8 stage over LDS using the LDS twiddle table Wt[t]=e^{-2pi i t/8192}.
// ---------------------------------------------------------------------------
template<int DIR, int NTHR, int LM>
__device__ __forceinline__ void r8_stage_t(cf* Z, const cf* Wt, int tid) {
    const int m = 1 << LM;
#pragma unroll
    for (int q = 0; q < 1024 / NTHR; ++q) {
        int beta = q * NTHR + tid;
        int j = beta & (m - 1);
        int g = beta >> LM;
        int base = (g << (LM + 3)) + j;
        cf a[8];
#pragma unroll
        for (int r = 0; r < 8; ++r) a[r] = Z[PADI(base + (r << LM))];
        cf w1 = Wt[j << (10 - LM)];
        if (DIR > 0) w1.y = -w1.y;
        cf w[8];
        twpow(w1, w);
        if (DIR > 0) {
#pragma unroll
            for (int k = 1; k < 8; ++k) a[k] = cmul(a[k], w[k]);
        }
        dft8<DIR>(a);
        if (DIR < 0) {
#pragma unroll
            for (int k = 1; k < 8; ++k) a[k] = cmul(a[k], w[k]);
        }
#pragma unroll
        for (int r = 0; r < 8; ++r) Z[PADI(base + (r << LM))] = a[r];
    }
}

// radix-2 stage on adjacent pairs (build_V only)
template<int NTHR>
__device__ __forceinline__ void r2_stage(cf* Z, int tid) {
#pragma unroll
    for (int q = 0; q < 4096 / NTHR; ++q) {
        int beta = q * NTHR + tid;
        int i0 = PADI(2 * beta), i1 = i0 + 1;
        cf a = Z[i0], b = Z[i1];
        Z[i0] = a + b;
        Z[i1] = a - b;
    }
}

// sincos-based radix-8 stage (build_V only; runs once)
template<int DIR, int NTHR>
__device__ __forceinline__ void r8_stage(cf* Z, int lm, int tid) {
    const int m = 1 << lm;
    const float ang0 = ((DIR < 0) ? -6.2831853071795865f : 6.2831853071795865f)
                       / (float)(m * 8);
#pragma unroll
    for (int q = 0; q < 1024 / NTHR; ++q) {
        int beta = q * NTHR + tid;
        int j = beta & (m - 1);
        int g = beta >> lm;
        int base = (g << (lm + 3)) + j;
        cf a[8];
#pragma unroll
        for (int r = 0; r < 8; ++r) a[r] = Z[PADI(base + (r << lm))];
        float sn, cs;
        __sincosf(ang0 * (float)j, &sn, &cs);
        cf w[8];
        twpow((cf){cs, sn}, w);
        if (DIR > 0) {
#pragma unroll
            for (int k = 1; k < 8; ++k) a[k] = cmul(a[k], w[k]);
        }
        dft8<DIR>(a);
        if (DIR < 0) {
#pragma unroll
            for (int k = 1; k < 8; ++k) a[k] = cmul(a[k], w[k]);
        }
#pragma unroll
        for (int r = 0; r < 8; ++r) Z[PADI(base + (r << lm))] = a[r];
    }
}

// ---------------------------------------------------------------------------
// Kernel 1 (fused prep): block 0 builds V-hat (full DIF chain incl. r2,
// digit-reversed, pre-scaled 1/8192); blocks 1..4096 transpose+convert
// xT[b][d][j] = bf16(x[b][j][d]).  512 threads.  LDS aliased.
// ---------------------------------------------------------------------------
__global__ __launch_bounds__(512) void prep(const float* __restrict__ x,
                                            const float* __restrict__ pos,
                                            const float* __restrict__ zero,
                                            const float* __restrict__ neg,
                                            unsigned short* __restrict__ xT,
                                            cf* __restrict__ Vh) {
    __shared__ cf Z[PADI(FN)];
    int tid = threadIdx.x;
    if (blockIdx.x == 0) {
        float zv = zero[0];
#pragma unroll
        for (int q = 0; q < 16; ++q) {
            int t = q * 512 + tid;
            float v;
            if (t == 0 || t == NSEQ) v = zv;
            else if (t < NSEQ)       v = pos[t - 1];
            else                     v = neg[t - NSEQ - 1];
            v = fminf(fmaxf(v, -60.0f), 30.0f);
            Z[PADI(t)] = (cf){__expf(v), 0.0f};
        }
        __syncthreads();
        r8_stage<-1, 512>(Z, 10, tid); __syncthreads();
        r8_stage<-1, 512>(Z, 7,  tid); __syncthreads();
        r8_stage<-1, 512>(Z, 4,  tid); __syncthreads();
        r8_stage<-1, 512>(Z, 1,  tid); __syncthreads();
        r2_stage<512>(Z, tid);         __syncthreads();
        const float sc = 1.0f / (float)FN;
#pragma unroll
        for (int q = 0; q < 16; ++q) {
            int i = q * 512 + tid;
            Vh[i] = Z[PADI(i)] * sc;
        }
    } else {
        unsigned short (*tl)[72] = (unsigned short (*)[72])Z;   // alias LDS
        int t   = blockIdx.x - 1;
        int b   = t >> 9;
        int rem = t & 511;
        int j0  = (rem >> 3) << 6;
        int d0  = (rem & 7) << 6;
        const float* xb = x + (size_t)b * NSEQ * DDIM;
#pragma unroll
        for (int e = 0; e < 2; ++e) {
            int idx = e * 512 + tid;
            int r   = idx >> 4;
            int c4  = (idx & 15) << 2;
            float4 v = *(const float4*)&xb[(size_t)(j0 + r) * DDIM + d0 + c4];
            ushort4 o;
            o.x = f2bf(v.x); o.y = f2bf(v.y); o.z = f2bf(v.z); o.w = f2bf(v.w);
            *(ushort4*)&tl[r][c4] = o;
        }
        __syncthreads();
        unsigned short* xtb = xT + (size_t)b * DDIM * NSEQ;
#pragma unroll
        for (int e = 0; e < 2; ++e) {
            int idx = e * 512 + tid;
            int d   = idx >> 4;
            int jq  = (idx & 15) << 2;
            ushort4 o;
            o.x = tl[jq + 0][d]; o.y = tl[jq + 1][d];
            o.z = tl[jq + 2][d]; o.w = tl[jq + 3][d];
            *(ushort4*)&xtb[(size_t)(d0 + d) * NSEQ + j0 + jq] = o;
        }
    }
}

// ---------------------------------------------------------------------------
// Kernel 2: per column-pair FFT convolution.  512 threads, 2 blocks/CU,
// __launch_bounds__(512,4) -> 128 VGPR cap (r14 spill lesson).  LDS twiddle
// table; fused first/last stages; merged fwd-lm1 + R2 diag(Vh) R2 + inv-lm1
// register pass with shfl_xor pairing; packed f32 complex math throughout.
// ---------------------------------------------------------------------------
__global__ __launch_bounds__(512, 4) void fft_conv(unsigned short* __restrict__ xT,
                                                   const cf* __restrict__ Vh) {
    __shared__ cf Z[PADI(FN)];
    __shared__ cf Wt[1024];
    int tid = threadIdx.x;
    int blk = blockIdx.x;
    int b   = blk >> 8;
    int dp  = blk & 255;
    unsigned short* col0 = xT + ((size_t)(b * DDIM + 2 * dp)) * NSEQ;
    unsigned short* col1 = col0 + NSEQ;

    // ---- build twiddle table: Wt[t] = e^{-2pi i t / 8192} ----
#pragma unroll
    for (int q = 0; q < 2; ++q) {
        int t = q * 512 + tid;
        float sn, cs;
        __sincosf(-7.66990393942820625e-04f * (float)t, &sn, &cs);
        Wt[t] = (cf){cs, sn};
    }
    __syncthreads();

    // ---- fused load + first forward stage (lm=10, half-zero) ----
#pragma unroll
    for (int q = 0; q < 2; ++q) {
        int j = q * 512 + tid;
        cf a0 = {bf2f(col0[j]),        bf2f(col1[j])};
        cf a1 = {bf2f(col0[j + 1024]), bf2f(col1[j + 1024])};
        cf a2 = {bf2f(col0[j + 2048]), bf2f(col1[j + 2048])};
        cf a3 = {bf2f(col0[j + 3072]), bf2f(col1[j + 3072])};
        cf a[8];
        dft8_half<-1>(a0, a1, a2, a3, a);
        cf w[8];
        twpow(Wt[j], w);
#pragma unroll
        for (int k = 1; k < 8; ++k) a[k] = cmul(a[k], w[k]);
#pragma unroll
        for (int r = 0; r < 8; ++r) Z[PADI(j + (r << 10))] = a[r];
    }
    __syncthreads();

    r8_stage_t<-1, 512, 7>(Z, Wt, tid);  __syncthreads();
    r8_stage_t<-1, 512, 4>(Z, Wt, tid);  __syncthreads();

    // ---- merged: fwd lm=1 + R2 diag(Vh) R2 + inv lm=1, in registers ----
    const float4* V4 = (const float4*)Vh;
#pragma unroll
    for (int q = 0; q < 2; ++q) {
        const int idx = q * 512 + tid;
        const int g  = idx >> 1;      // group 0..511
        const int jj = idx & 1;       // == tid&1 -> lane-adjacent pairing
        const int base = g * 16 + jj;
        cf a[8];
#pragma unroll
        for (int r = 0; r < 8; ++r) a[r] = Z[PADI(base + 2 * r)];
        dft8<-1>(a);
        // lm=1 fwd twiddles: w1 = e^{-i pi k/8} for jj=1, compile-time consts
        const float C1 = 0.92387953251128674f, S1 = 0.38268343236508977f;
        const float C2 = 0.70710678118654752f;
        if (jj) {
            a[1] = cmul(a[1], (cf){C1, -S1});
            a[2] = cmul(a[2], (cf){C2, -C2});
            a[3] = cmul(a[3], (cf){S1, -C1});
            a[4] = crot<-1>(a[4]);
            a[5] = cmul(a[5], (cf){-S1, -C1});
            a[6] = cmul(a[6], (cf){-C2, -C2});
            a[7] = cmul(a[7], (cf){-C1, -S1});
        }
        // pair (2p,2p+1) = (even-lane a[r], odd-lane a[r]), p = g*8+r
#pragma unroll
        for (int r = 0; r < 8; ++r) {
            cf own = a[r];
            cf oth;
            oth.x = __shfl_xor(own.x, 1);
            oth.y = __shfl_xor(own.y, 1);
            float4 v = V4[g * 8 + r];
            cf V0 = {v.x, v.y}, V1 = {v.z, v.w};
            cf Vp = V0 + V1, Vm = V0 - V1;
            a[r] = cmul(Vp, own) + cmul(Vm, oth);
        }
        // inv lm=1: twiddle first (conjugates), then dft8<+1>
        if (jj) {
            a[1] = cmul(a[1], (cf){C1, S1});
            a[2] = cmul(a[2], (cf){C2, C2});
            a[3] = cmul(a[3], (cf){S1, C1});
            a[4] = crot<1>(a[4]);
            a[5] = cmul(a[5], (cf){-S1, C1});
            a[6] = cmul(a[6], (cf){-C2, C2});
            a[7] = cmul(a[7], (cf){-C1, S1});
        }
        dft8<1>(a);
#pragma unroll
        for (int r = 0; r < 8; ++r) Z[PADI(base + 2 * r)] = a[r];
    }
    __syncthreads();

    r8_stage_t<1, 512, 4>(Z, Wt, tid);   __syncthreads();
    r8_stage_t<1, 512, 7>(Z, Wt, tid);   __syncthreads();

    // ---- fused last inverse stage (lm=10) + store (only idx < 4096) ----
#pragma unroll
    for (int q = 0; q < 2; ++q) {
        int j = q * 512 + tid;
        cf a[8];
#pragma unroll
        for (int r = 0; r < 8; ++r) a[r] = Z[PADI(j + (r << 10))];
        cf w1 = Wt[j];
        w1.y = -w1.y;
        cf w[8];
        twpow(w1, w);
#pragma unroll
        for (int k = 1; k < 8; ++k) a[k] = cmul(a[k], w[k]);
        dft8<1>(a);
#pragma unroll
        for (int r = 0; r < 4; ++r) {
            col0[j + (r << 10)] = f2bf(a[r].x);
            col1[j + (r << 10)] = f2bf(a[r].y);
        }
    }
}

// ---------------------------------------------------------------------------
// Kernel 3: un-transpose  out[b][j][d] = f32(outT[b][d][j]).  grid (64,8,8).
// ---------------------------------------------------------------------------
__global__ void untranspose(const unsigned short* __restrict__ oT,
                            float* __restrict__ out) {
    __shared__ unsigned short tl[64][65];
    int j0 = blockIdx.x * 64, d0 = blockIdx.y * 64, b = blockIdx.z;
    const unsigned short* src = oT + (size_t)b * DDIM * NSEQ;
#pragma unroll
    for (int e = 0; e < 16; ++e) {
        int idx = e * 256 + threadIdx.x;
        int r = idx >> 6, c = idx & 63;
        tl[r][c] = src[(size_t)(d0 + r) * NSEQ + j0 + c];
    }
    __syncthreads();
    float* dst = out + ((size_t)b * NSEQ + j0) * DDIM + d0;
#pragma unroll
    for (int e = 0; e < 16; ++e) {
        int idx = e * 256 + threadIdx.x;
        int r = idx >> 6, c = idx & 63;
        dst[(size_t)r * DDIM + c] = bf2f(tl[c][r]);
    }
}

// ---------------------------------------------------------------------------
extern "C" void kernel_launch(void* const* d_in, const int* in_sizes, int n_in,
                              void* d_out, int out_size, void* d_ws, size_t ws_size,
                              hipStream_t stream) {
    const float* x    = (const float*)d_in[0];
    const float* pos  = (const float*)d_in[1];
    const float* zero = (const float*)d_in[2];
    const float* neg  = (const float*)d_in[3];
    float* out = (float*)d_out;

    unsigned short* xT = (unsigned short*)d_ws;                       // 32 MiB
    cf* Vh = (cf*)((char*)d_ws + (size_t)32 * 1024 * 1024);           // 64 KiB

    prep<<<dim3(4097), 512, 0, stream>>>(x, pos, zero, neg, xT, Vh);
    fft_conv<<<dim3(NB * 256), 512, 0, stream>>>(xT, Vh);
    untranspose<<<dim3(64, 8, 8), 256, 0, stream>>>(xT, out);
}

// Round 17
// 107.891 us; speedup vs baseline: 1.5315x; 1.0412x over previous
//
#include <hip/hip_runtime.h>
#include <hip/hip_bf16.h>
#include <stdint.h>

#define NSEQ 4096
#define DDIM 512
#define NB   8
#define FN   8192          // FFT length = 2*NSEQ

// pad every 16 elements: cf is 8 B, bank-pair index = idx mod 16.
// (i + i/16) makes stride-16 groups rotate across bank-pairs (merged pass
// was 2x-conflicted with the old i + i/32 pad).
#define PADI(i) ((i) + ((i) >> 4))

struct __align__(8) cf { float x, y; };

__device__ __forceinline__ cf cadd(cf a, cf b) { return {a.x + b.x, a.y + b.y}; }
__device__ __forceinline__ cf csub(cf a, cf b) { return {a.x - b.x, a.y - b.y}; }
__device__ __forceinline__ cf cmul(cf a, cf b) {
    return {a.x * b.x - a.y * b.y, a.x * b.y + a.y * b.x};
}
template<int DIR> __device__ __forceinline__ cf crot(cf z) {  // *(-i) fwd, *(+i) inv
    return DIR < 0 ? cf{z.y, -z.x} : cf{-z.y, z.x};
}

__device__ __forceinline__ unsigned short f2bf(float f) {
    union { float f; unsigned int u; } v;
    v.f = f;
    unsigned int u = v.u;
    u += 0x7FFFu + ((u >> 16) & 1u);   // RNE
    return (unsigned short)(u >> 16);
}
__device__ __forceinline__ float bf2f(unsigned short u) {
    union { unsigned int i; float f; } v;
    v.i = (unsigned int)u << 16;
    return v.f;
}

// ---------------------------------------------------------------------------
// 8-point DFT pieces
// ---------------------------------------------------------------------------
template<int DIR>
__device__ __forceinline__ void fft4(cf& b0, cf& b1, cf& b2, cf& b3) {
    cf s0 = cadd(b0, b2), s1 = csub(b0, b2);
    cf s2 = cadd(b1, b3), s3 = crot<DIR>(csub(b1, b3));
    b0 = cadd(s0, s2); b1 = cadd(s1, s3);
    b2 = csub(s0, s2); b3 = csub(s1, s3);
}

template<int DIR>
__device__ __forceinline__ void dft8(cf a[8]) {
    cf e0 = a[0], e1 = a[2], e2 = a[4], e3 = a[6];
    cf o0 = a[1], o1 = a[3], o2 = a[5], o3 = a[7];
    fft4<DIR>(e0, e1, e2, e3);
    fft4<DIR>(o0, o1, o2, o3);
    const float c = 0.70710678118654752f;
    cf w1 = (DIR < 0) ? cf{c, -c} : cf{c, c};
    cf w3 = (DIR < 0) ? cf{-c, -c} : cf{-c, c};
    o1 = cmul(o1, w1);
    o2 = crot<DIR>(o2);
    o3 = cmul(o3, w3);
    a[0] = cadd(e0, o0); a[1] = cadd(e1, o1); a[2] = cadd(e2, o2); a[3] = cadd(e3, o3);
    a[4] = csub(e0, o0); a[5] = csub(e1, o1); a[6] = csub(e2, o2); a[7] = csub(e3, o3);
}

// DFT8 with a[4..7] == 0 (zero-padded upper half), inputs a0..a3
template<int DIR>
__device__ __forceinline__ void dft8_half(cf a0, cf a1, cf a2, cf a3, cf a[8]) {
    cf r2 = crot<DIR>(a2), r3 = crot<DIR>(a3);
    cf e0 = cadd(a0, a2), e1 = cadd(a0, r2), e2 = csub(a0, a2), e3 = csub(a0, r2);
    cf o0 = cadd(a1, a3), o1 = cadd(a1, r3), o2 = csub(a1, a3), o3 = csub(a1, r3);
    const float c = 0.70710678118654752f;
    cf w1 = (DIR < 0) ? cf{c, -c} : cf{c, c};
    cf w3 = (DIR < 0) ? cf{-c, -c} : cf{-c, c};
    o1 = cmul(o1, w1);
    o2 = crot<DIR>(o2);
    o3 = cmul(o3, w3);
    a[0] = cadd(e0, o0); a[1] = cadd(e1, o1); a[2] = cadd(e2, o2); a[3] = cadd(e3, o3);
    a[4] = csub(e0, o0); a[5] = csub(e1, o1); a[6] = csub(e2, o2); a[7] = csub(e3, o3);
}

// depth-3 twiddle powers w[k] = w1^k, k=1..7
__device__ __forceinline__ void twpow(cf w1, cf w[8]) {
    w[1] = w1;
    w[2] = cmul(w1, w1);
    w[3] = cmul(w[2], w1);
    w[4] = cmul(w[2], w[2]);
    w[5] = cmul(w[4], w1);
    w[6] = cmul(w[4], w[2]);
    w[7] = cmul(w[4], w[3]);
}

// ---------------------------------------------------------------------------
// radix-8 stage over LDS using the LDS twiddle table Wt[t]=e^{-2pi i t/8192}.
// ---------------------------------------------------------------------------
template<int DIR, int NTHR, int LM>
__device__ __forceinline__ void r8_stage_t(cf* Z, const cf* Wt, int tid) {
    const int m = 1 << LM;
#pragma unroll
    for (int q = 0; q < 1024 / NTHR; ++q) {
        int beta = q * NTHR + tid;
        int j = beta & (m - 1);
        int g = beta >> LM;
        int base = (g << (LM + 3)) + j;
        cf a[8];
#pragma unroll
        for (int r = 0; r < 8; ++r) a[r] = Z[PADI(base + (r << LM))];
        cf w1 = Wt[j << (10 - LM)];
        if (DIR > 0) w1.y = -w1.y;
        cf w[8];
        twpow(w1, w);
        if (DIR > 0) {
#pragma unroll
            for (int k = 1; k < 8; ++k) a[k] = cmul(a[k], w[k]);
        }
        dft8<DIR>(a);
        if (DIR < 0) {
#pragma unroll
            for (int k = 1; k < 8; ++k) a[k] = cmul(a[k], w[k]);
        }
#pragma unroll
        for (int r = 0; r < 8; ++r) Z[PADI(base + (r << LM))] = a[r];
    }
}

// radix-2 stage on adjacent pairs (build_V only; PADI16 keeps pairs adjacent)
template<int NTHR>
__device__ __forceinline__ void r2_stage(cf* Z, int tid) {
#pragma unroll
    for (int q = 0; q < 4096 / NTHR; ++q) {
        int beta = q * NTHR + tid;
        int i0 = PADI(2 * beta), i1 = i0 + 1;
        cf a = Z[i0], b = Z[i1];
        Z[i0] = cadd(a, b);
        Z[i1] = csub(a, b);
    }
}

// sincos-based radix-8 stage (build_V only; runs once)
template<int DIR, int NTHR>
__device__ __forceinline__ void r8_stage(cf* Z, int lm, int tid) {
    const int m = 1 << lm;
    const float ang0 = ((DIR < 0) ? -6.2831853071795865f : 6.2831853071795865f)
                       / (float)(m * 8);
#pragma unroll
    for (int q = 0; q < 1024 / NTHR; ++q) {
        int beta = q * NTHR + tid;
        int j = beta & (m - 1);
        int g = beta >> lm;
        int base = (g << (lm + 3)) + j;
        cf a[8];
#pragma unroll
        for (int r = 0; r < 8; ++r) a[r] = Z[PADI(base + (r << lm))];
        float sn, cs;
        __sincosf(ang0 * (float)j, &sn, &cs);
        cf w[8];
        twpow({cs, sn}, w);
        if (DIR > 0) {
#pragma unroll
            for (int k = 1; k < 8; ++k) a[k] = cmul(a[k], w[k]);
        }
        dft8<DIR>(a);
        if (DIR < 0) {
#pragma unroll
            for (int k = 1; k < 8; ++k) a[k] = cmul(a[k], w[k]);
        }
#pragma unroll
        for (int r = 0; r < 8; ++r) Z[PADI(base + (r << lm))] = a[r];
    }
}

// ---------------------------------------------------------------------------
// Kernel 1 (fused prep): block 0 builds V-hat (full DIF chain incl. r2,
// digit-reversed, pre-scaled 1/8192); blocks 1..4096 transpose+convert
// xT[b][d][j] = bf16(x[b][j][d]).  512 threads.  LDS aliased.
// ---------------------------------------------------------------------------
__global__ __launch_bounds__(512) void prep(const float* __restrict__ x,
                                            const float* __restrict__ pos,
                                            const float* __restrict__ zero,
                                            const float* __restrict__ neg,
                                            unsigned short* __restrict__ xT,
                                            cf* __restrict__ Vh) {
    __shared__ cf Z[PADI(FN) + 2];
    int tid = threadIdx.x;
    if (blockIdx.x == 0) {
        float zv = zero[0];
#pragma unroll
        for (int q = 0; q < 16; ++q) {
            int t = q * 512 + tid;
            float v;
            if (t == 0 || t == NSEQ) v = zv;
            else if (t < NSEQ)       v = pos[t - 1];
            else                     v = neg[t - NSEQ - 1];
            v = fminf(fmaxf(v, -60.0f), 30.0f);
            Z[PADI(t)] = {__expf(v), 0.0f};
        }
        __syncthreads();
        r8_stage<-1, 512>(Z, 10, tid); __syncthreads();
        r8_stage<-1, 512>(Z, 7,  tid); __syncthreads();
        r8_stage<-1, 512>(Z, 4,  tid); __syncthreads();
        r8_stage<-1, 512>(Z, 1,  tid); __syncthreads();
        r2_stage<512>(Z, tid);         __syncthreads();
        const float sc = 1.0f / (float)FN;
#pragma unroll
        for (int q = 0; q < 16; ++q) {
            int i = q * 512 + tid;
            cf v = Z[PADI(i)];
            Vh[i] = {v.x * sc, v.y * sc};
        }
    } else {
        unsigned short (*tl)[72] = (unsigned short (*)[72])Z;   // alias LDS
        int t   = blockIdx.x - 1;
        int b   = t >> 9;
        int rem = t & 511;
        int j0  = (rem >> 3) << 6;
        int d0  = (rem & 7) << 6;
        const float* xb = x + (size_t)b * NSEQ * DDIM;
#pragma unroll
        for (int e = 0; e < 2; ++e) {
            int idx = e * 512 + tid;
            int r   = idx >> 4;
            int c4  = (idx & 15) << 2;
            float4 v = *(const float4*)&xb[(size_t)(j0 + r) * DDIM + d0 + c4];
            ushort4 o;
            o.x = f2bf(v.x); o.y = f2bf(v.y); o.z = f2bf(v.z); o.w = f2bf(v.w);
            *(ushort4*)&tl[r][c4] = o;
        }
        __syncthreads();
        unsigned short* xtb = xT + (size_t)b * DDIM * NSEQ;
#pragma unroll
        for (int e = 0; e < 2; ++e) {
            int idx = e * 512 + tid;
            int d   = idx >> 4;
            int jq  = (idx & 15) << 2;
            ushort4 o;
            o.x = tl[jq + 0][d]; o.y = tl[jq + 1][d];
            o.z = tl[jq + 2][d]; o.w = tl[jq + 3][d];
            *(ushort4*)&xtb[(size_t)(d0 + d) * NSEQ + j0 + jq] = o;
        }
    }
}

// ---------------------------------------------------------------------------
// Kernel 2: per column-pair FFT convolution.  512 threads, 2 blocks/CU,
// __launch_bounds__(512,4) -> 128 VGPR cap (r14 spill lesson).  LDS twiddle
// table; fused first/last stages; merged fwd-lm1 + R2 diag(Vh) R2 + inv-lm1
// register pass with shfl_xor pairing.  PADI16 pad: conflict-free merged pass.
// ---------------------------------------------------------------------------
__global__ __launch_bounds__(512, 4) void fft_conv(unsigned short* __restrict__ xT,
                                                   const cf* __restrict__ Vh) {
    __shared__ cf Z[PADI(FN) + 2];
    __shared__ cf Wt[1024];
    int tid = threadIdx.x;
    int blk = blockIdx.x;
    int b   = blk >> 8;
    int dp  = blk & 255;
    unsigned short* col0 = xT + ((size_t)(b * DDIM + 2 * dp)) * NSEQ;
    unsigned short* col1 = col0 + NSEQ;

    // ---- build twiddle table: Wt[t] = e^{-2pi i t / 8192} ----
#pragma unroll
    for (int q = 0; q < 2; ++q) {
        int t = q * 512 + tid;
        float sn, cs;
        __sincosf(-7.66990393942820625e-04f * (float)t, &sn, &cs);
        Wt[t] = {cs, sn};
    }
    __syncthreads();

    // ---- fused load + first forward stage (lm=10, half-zero) ----
#pragma unroll
    for (int q = 0; q < 2; ++q) {
        int j = q * 512 + tid;
        cf a0 = {bf2f(col0[j]),        bf2f(col1[j])};
        cf a1 = {bf2f(col0[j + 1024]), bf2f(col1[j + 1024])};
        cf a2 = {bf2f(col0[j + 2048]), bf2f(col1[j + 2048])};
        cf a3 = {bf2f(col0[j + 3072]), bf2f(col1[j + 3072])};
        cf a[8];
        dft8_half<-1>(a0, a1, a2, a3, a);
        cf w[8];
        twpow(Wt[j], w);
#pragma unroll
        for (int k = 1; k < 8; ++k) a[k] = cmul(a[k], w[k]);
#pragma unroll
        for (int r = 0; r < 8; ++r) Z[PADI(j + (r << 10))] = a[r];
    }
    __syncthreads();

    r8_stage_t<-1, 512, 7>(Z, Wt, tid);  __syncthreads();
    r8_stage_t<-1, 512, 4>(Z, Wt, tid);  __syncthreads();

    // ---- merged: fwd lm=1 + R2 diag(Vh) R2 + inv lm=1, in registers ----
    const float4* V4 = (const float4*)Vh;
#pragma unroll
    for (int q = 0; q < 2; ++q) {
        const int idx = q * 512 + tid;
        const int g  = idx >> 1;      // group 0..511
        const int jj = idx & 1;       // == tid&1 -> lane-adjacent pairing
        const int base = g * 16 + jj;
        cf a[8];
#pragma unroll
        for (int r = 0; r < 8; ++r) a[r] = Z[PADI(base + 2 * r)];
        dft8<-1>(a);
        // lm=1 fwd twiddles: w1 = e^{-i pi k/8} for jj=1, compile-time consts
        const float C1 = 0.92387953251128674f, S1 = 0.38268343236508977f;
        const float C2 = 0.70710678118654752f;
        if (jj) {
            a[1] = cmul(a[1], {C1, -S1});
            a[2] = cmul(a[2], {C2, -C2});
            a[3] = cmul(a[3], {S1, -C1});
            a[4] = crot<-1>(a[4]);
            a[5] = cmul(a[5], {-S1, -C1});
            a[6] = cmul(a[6], {-C2, -C2});
            a[7] = cmul(a[7], {-C1, -S1});
        }
        // pair (2p,2p+1) = (even-lane a[r], odd-lane a[r]), p = g*8+r
#pragma unroll
        for (int r = 0; r < 8; ++r) {
            cf own = a[r];
            cf oth;
            oth.x = __shfl_xor(own.x, 1);
            oth.y = __shfl_xor(own.y, 1);
            float4 v = V4[g * 8 + r];
            cf V0 = {v.x, v.y}, V1 = {v.z, v.w};
            cf Vp = cadd(V0, V1), Vm = csub(V0, V1);
            a[r] = cadd(cmul(Vp, own), cmul(Vm, oth));
        }
        // inv lm=1: twiddle first (conjugates), then dft8<+1>
        if (jj) {
            a[1] = cmul(a[1], {C1, S1});
            a[2] = cmul(a[2], {C2, C2});
            a[3] = cmul(a[3], {S1, C1});
            a[4] = crot<1>(a[4]);
            a[5] = cmul(a[5], {-S1, C1});
            a[6] = cmul(a[6], {-C2, C2});
            a[7] = cmul(a[7], {-C1, S1});
        }
        dft8<1>(a);
#pragma unroll
        for (int r = 0; r < 8; ++r) Z[PADI(base + 2 * r)] = a[r];
    }
    __syncthreads();

    r8_stage_t<1, 512, 4>(Z, Wt, tid);   __syncthreads();
    r8_stage_t<1, 512, 7>(Z, Wt, tid);   __syncthreads();

    // ---- fused last inverse stage (lm=10) + store (only idx < 4096) ----
#pragma unroll
    for (int q = 0; q < 2; ++q) {
        int j = q * 512 + tid;
        cf a[8];
#pragma unroll
        for (int r = 0; r < 8; ++r) a[r] = Z[PADI(j + (r << 10))];
        cf w1 = Wt[j];
        w1.y = -w1.y;
        cf w[8];
        twpow(w1, w);
#pragma unroll
        for (int k = 1; k < 8; ++k) a[k] = cmul(a[k], w[k]);
        dft8<1>(a);
#pragma unroll
        for (int r = 0; r < 4; ++r) {
            col0[j + (r << 10)] = f2bf(a[r].x);
            col1[j + (r << 10)] = f2bf(a[r].y);
        }
    }
}

// ---------------------------------------------------------------------------
// Kernel 3: un-transpose  out[b][j][d] = f32(outT[b][d][j]).  grid (64,8,8).
// ---------------------------------------------------------------------------
__global__ void untranspose(const unsigned short* __restrict__ oT,
                            float* __restrict__ out) {
    __shared__ unsigned short tl[64][65];
    int j0 = blockIdx.x * 64, d0 = blockIdx.y * 64, b = blockIdx.z;
    const unsigned short* src = oT + (size_t)b * DDIM * NSEQ;
#pragma unroll
    for (int e = 0; e < 16; ++e) {
        int idx = e * 256 + threadIdx.x;
        int r = idx >> 6, c = idx & 63;
        tl[r][c] = src[(size_t)(d0 + r) * NSEQ + j0 + c];
    }
    __syncthreads();
    float* dst = out + ((size_t)b * NSEQ + j0) * DDIM + d0;
#pragma unroll
    for (int e = 0; e < 16; ++e) {
        int idx = e * 256 + threadIdx.x;
        int r = idx >> 6, c = idx & 63;
        dst[(size_t)r * DDIM + c] = bf2f(tl[c][r]);
    }
}

// ---------------------------------------------------------------------------
extern "C" void kernel_launch(void* const* d_in, const int* in_sizes, int n_in,
                              void* d_out, int out_size, void* d_ws, size_t ws_size,
                              hipStream_t stream) {
    const float* x    = (const float*)d_in[0];
    const float* pos  = (const float*)d_in[1];
    const float* zero = (const float*)d_in[2];
    const float* neg  = (const float*)d_in[3];
    float* out = (float*)d_out;

    unsigned short* xT = (unsigned short*)d_ws;                       // 32 MiB
    cf* Vh = (cf*)((char*)d_ws + (size_t)32 * 1024 * 1024);           // 64 KiB

    prep<<<dim3(4097), 512, 0, stream>>>(x, pos, zero, neg, xT, Vh);
    fft_conv<<<dim3(NB * 256), 512, 0, stream>>>(xT, Vh);
    untranspose<<<dim3(64, 8, 8), 256, 0, stream>>>(xT, out);
}

// Round 18
// 97.007 us; speedup vs baseline: 1.7034x; 1.1122x over previous
//
#include <hip/hip_runtime.h>
#include <hip/hip_bf16.h>
#include <stdint.h>

#define NSEQ 4096
#define DDIM 512
#define NB   8
#define FN   8192          // FFT length = 2*NSEQ

#define PADI(i) ((i) + ((i) >> 4))

struct __align__(8) cf { float x, y; };

__device__ __forceinline__ cf cadd(cf a, cf b) { return {a.x + b.x, a.y + b.y}; }
__device__ __forceinline__ cf csub(cf a, cf b) { return {a.x - b.x, a.y - b.y}; }
__device__ __forceinline__ cf cmul(cf a, cf b) {
    return {a.x * b.x - a.y * b.y, a.x * b.y + a.y * b.x};
}
__device__ __forceinline__ cf cmulc(cf a, cf b) {   // a * conj(b)
    return {a.x * b.x + a.y * b.y, a.y * b.x - a.x * b.y};
}
template<int DIR> __device__ __forceinline__ cf crot(cf z) {  // *(-i) fwd, *(+i) inv
    return DIR < 0 ? cf{z.y, -z.x} : cf{-z.y, z.x};
}

__device__ __forceinline__ unsigned short f2bf(float f) {
    union { float f; unsigned int u; } v;
    v.f = f;
    unsigned int u = v.u;
    u += 0x7FFFu + ((u >> 16) & 1u);   // RNE
    return (unsigned short)(u >> 16);
}
__device__ __forceinline__ float bf2f(unsigned short u) {
    union { unsigned int i; float f; } v;
    v.i = (unsigned int)u << 16;
    return v.f;
}

// ---------------------------------------------------------------------------
// 8-point DFT pieces
// ---------------------------------------------------------------------------
template<int DIR>
__device__ __forceinline__ void fft4(cf& b0, cf& b1, cf& b2, cf& b3) {
    cf s0 = cadd(b0, b2), s1 = csub(b0, b2);
    cf s2 = cadd(b1, b3), s3 = crot<DIR>(csub(b1, b3));
    b0 = cadd(s0, s2); b1 = cadd(s1, s3);
    b2 = csub(s0, s2); b3 = csub(s1, s3);
}

template<int DIR>
__device__ __forceinline__ void dft8(cf a[8]) {
    cf e0 = a[0], e1 = a[2], e2 = a[4], e3 = a[6];
    cf o0 = a[1], o1 = a[3], o2 = a[5], o3 = a[7];
    fft4<DIR>(e0, e1, e2, e3);
    fft4<DIR>(o0, o1, o2, o3);
    const float c = 0.70710678118654752f;
    cf w1 = (DIR < 0) ? cf{c, -c} : cf{c, c};
    cf w3 = (DIR < 0) ? cf{-c, -c} : cf{-c, c};
    o1 = cmul(o1, w1);
    o2 = crot<DIR>(o2);
    o3 = cmul(o3, w3);
    a[0] = cadd(e0, o0); a[1] = cadd(e1, o1); a[2] = cadd(e2, o2); a[3] = cadd(e3, o3);
    a[4] = csub(e0, o0); a[5] = csub(e1, o1); a[6] = csub(e2, o2); a[7] = csub(e3, o3);
}

// DFT8 with a[4..7] == 0 (zero-padded upper half), inputs a0..a3
template<int DIR>
__device__ __forceinline__ void dft8_half(cf a0, cf a1, cf a2, cf a3, cf a[8]) {
    cf r2 = crot<DIR>(a2), r3 = crot<DIR>(a3);
    cf e0 = cadd(a0, a2), e1 = cadd(a0, r2), e2 = csub(a0, a2), e3 = csub(a0, r2);
    cf o0 = cadd(a1, a3), o1 = cadd(a1, r3), o2 = csub(a1, a3), o3 = csub(a1, r3);
    const float c = 0.70710678118654752f;
    cf w1 = (DIR < 0) ? cf{c, -c} : cf{c, c};
    cf w3 = (DIR < 0) ? cf{-c, -c} : cf{-c, c};
    o1 = cmul(o1, w1);
    o2 = crot<DIR>(o2);
    o3 = cmul(o3, w3);
    a[0] = cadd(e0, o0); a[1] = cadd(e1, o1); a[2] = cadd(e2, o2); a[3] = cadd(e3, o3);
    a[4] = csub(e0, o0); a[5] = csub(e1, o1); a[6] = csub(e2, o2); a[7] = csub(e3, o3);
}

// depth-3 twiddle powers w[k] = w1^k, k=1..7
__device__ __forceinline__ void twpow(cf w1, cf w[8]) {
    w[1] = w1;
    w[2] = cmul(w1, w1);
    w[3] = cmul(w[2], w1);
    w[4] = cmul(w[2], w[2]);
    w[5] = cmul(w[4], w1);
    w[6] = cmul(w[4], w[2]);
    w[7] = cmul(w[4], w[3]);
}

// ---------------------------------------------------------------------------
// radix-8 stage with LDS power table W7[t8*7+k-1] = w(8*t8)^k.
// fwd: dft8 then *w^k ; inv: *conj(w^k) then dft8.
// ---------------------------------------------------------------------------
template<int DIR, int LM, int TMUL>
__device__ __forceinline__ void r8_stage_tab(cf* Z, const cf* W7, int tid) {
    const int m = 1 << LM;
#pragma unroll
    for (int q = 0; q < 2; ++q) {
        int beta = q * 512 + tid;
        int j = beta & (m - 1);
        int g = beta >> LM;
        int base = (g << (LM + 3)) + j;
        cf a[8];
#pragma unroll
        for (int r = 0; r < 8; ++r) a[r] = Z[PADI(base + (r << LM))];
        cf w[8];
#pragma unroll
        for (int k = 1; k < 8; ++k) w[k] = W7[j * TMUL + k - 1];
        if (DIR > 0) {
#pragma unroll
            for (int k = 1; k < 8; ++k) a[k] = cmulc(a[k], w[k]);
        }
        dft8<DIR>(a);
        if (DIR < 0) {
#pragma unroll
            for (int k = 1; k < 8; ++k) a[k] = cmul(a[k], w[k]);
        }
#pragma unroll
        for (int r = 0; r < 8; ++r) Z[PADI(base + (r << LM))] = a[r];
    }
}

// radix-2 stage on adjacent pairs (build_V only)
template<int NTHR>
__device__ __forceinline__ void r2_stage(cf* Z, int tid) {
#pragma unroll
    for (int q = 0; q < 4096 / NTHR; ++q) {
        int beta = q * NTHR + tid;
        int i0 = PADI(2 * beta), i1 = i0 + 1;
        cf a = Z[i0], b = Z[i1];
        Z[i0] = cadd(a, b);
        Z[i1] = csub(a, b);
    }
}

// sincos-based radix-8 stage (build_V only; runs once)
template<int DIR, int NTHR>
__device__ __forceinline__ void r8_stage(cf* Z, int lm, int tid) {
    const int m = 1 << lm;
    const float ang0 = ((DIR < 0) ? -6.2831853071795865f : 6.2831853071795865f)
                       / (float)(m * 8);
#pragma unroll
    for (int q = 0; q < 1024 / NTHR; ++q) {
        int beta = q * NTHR + tid;
        int j = beta & (m - 1);
        int g = beta >> lm;
        int base = (g << (lm + 3)) + j;
        cf a[8];
#pragma unroll
        for (int r = 0; r < 8; ++r) a[r] = Z[PADI(base + (r << lm))];
        float sn, cs;
        __sincosf(ang0 * (float)j, &sn, &cs);
        cf w[8];
        twpow({cs, sn}, w);
        if (DIR > 0) {
#pragma unroll
            for (int k = 1; k < 8; ++k) a[k] = cmul(a[k], w[k]);
        }
        dft8<DIR>(a);
        if (DIR < 0) {
#pragma unroll
            for (int k = 1; k < 8; ++k) a[k] = cmul(a[k], w[k]);
        }
#pragma unroll
        for (int r = 0; r < 8; ++r) Z[PADI(base + (r << lm))] = a[r];
    }
}

// ---------------------------------------------------------------------------
// Kernel 1 (fused prep): block 0 builds the FOLDED mid-table Vt (from the
// DIF spectrum of exp(clamp(kernel)), pre-scaled 1/8192, with the lm1
// fwd/inv twiddles folded in); blocks 1..4096 transpose+convert x -> xT.
// Vt[2p]   = {Vp, Vm*wf(p&7)}        (even-lane coefficients A,B)
// Vt[2p+1] = {Vp, Vm*conj(wf(p&7))}  (odd-lane)
// where Vp = Vh[2p]+Vh[2p+1], Vm = Vh[2p]-Vh[2p+1], wf(r)=e^{-i pi r/8}.
// ---------------------------------------------------------------------------
__global__ __launch_bounds__(512) void prep(const float* __restrict__ x,
                                            const float* __restrict__ pos,
                                            const float* __restrict__ zero,
                                            const float* __restrict__ neg,
                                            unsigned short* __restrict__ xT,
                                            float4* __restrict__ Vt4) {
    __shared__ cf Z[PADI(FN)];
    int tid = threadIdx.x;
    if (blockIdx.x == 0) {
        float zv = zero[0];
#pragma unroll
        for (int q = 0; q < 16; ++q) {
            int t = q * 512 + tid;
            float v;
            if (t == 0 || t == NSEQ) v = zv;
            else if (t < NSEQ)       v = pos[t - 1];
            else                     v = neg[t - NSEQ - 1];
            v = fminf(fmaxf(v, -60.0f), 30.0f);
            Z[PADI(t)] = {__expf(v), 0.0f};
        }
        __syncthreads();
        r8_stage<-1, 512>(Z, 10, tid); __syncthreads();
        r8_stage<-1, 512>(Z, 7,  tid); __syncthreads();
        r8_stage<-1, 512>(Z, 4,  tid); __syncthreads();
        r8_stage<-1, 512>(Z, 1,  tid); __syncthreads();
        r2_stage<512>(Z, tid);         __syncthreads();
        const float sc = 1.0f / (float)FN;
#pragma unroll
        for (int q = 0; q < 16; ++q) {
            int i = q * 512 + tid;
            int p = i >> 1, r = p & 7;
            cf V0 = Z[PADI(2 * p)], V1 = Z[PADI(2 * p + 1)];
            cf Vp = {(V0.x + V1.x) * sc, (V0.y + V1.y) * sc};
            cf Vm = {(V0.x - V1.x) * sc, (V0.y - V1.y) * sc};
            float sn, cs;
            __sincosf(-0.39269908169872415f * (float)r, &sn, &cs);
            cf wf = {cs, sn};
            cf B = (i & 1) ? cmulc(Vm, wf) : cmul(Vm, wf);
            Vt4[i] = {Vp.x, Vp.y, B.x, B.y};
        }
    } else {
        unsigned short (*tl)[72] = (unsigned short (*)[72])Z;   // alias LDS
        int t   = blockIdx.x - 1;
        int b   = t >> 9;
        int rem = t & 511;
        int j0  = (rem >> 3) << 6;
        int d0  = (rem & 7) << 6;
        const float* xb = x + (size_t)b * NSEQ * DDIM;
#pragma unroll
        for (int e = 0; e < 2; ++e) {
            int idx = e * 512 + tid;
            int r   = idx >> 4;
            int c4  = (idx & 15) << 2;
            float4 v = *(const float4*)&xb[(size_t)(j0 + r) * DDIM + d0 + c4];
            ushort4 o;
            o.x = f2bf(v.x); o.y = f2bf(v.y); o.z = f2bf(v.z); o.w = f2bf(v.w);
            *(ushort4*)&tl[r][c4] = o;
        }
        __syncthreads();
        unsigned short* xtb = xT + (size_t)b * DDIM * NSEQ;
#pragma unroll
        for (int e = 0; e < 2; ++e) {
            int idx = e * 512 + tid;
            int d   = idx >> 4;
            int jq  = (idx & 15) << 2;
            ushort4 o;
            o.x = tl[jq + 0][d]; o.y = tl[jq + 1][d];
            o.z = tl[jq + 2][d]; o.w = tl[jq + 3][d];
            *(ushort4*)&xtb[(size_t)(d0 + d) * NSEQ + j0 + jq] = o;
        }
    }
}

// ---------------------------------------------------------------------------
// Kernel 2: per column-pair FFT convolution.  512 threads, 2 blocks/CU.
// Wt[512] (+compile-time j>=512 fixup) for fused first/last stages;
// W7[128][7] LDS power table for the 4 middle stages (no twpow there);
// merged middle pass uses precomputed folded Vt (no if(jj) twiddles).
// LDS = 69632(Z) + 4096(Wt) + 7168(W7) = 80896 B  ->  2 blocks/CU.
// ---------------------------------------------------------------------------
__global__ __launch_bounds__(512, 4) void fft_conv(unsigned short* __restrict__ xT,
                                                   const float4* __restrict__ Vt4) {
    __shared__ cf Z[PADI(FN)];
    __shared__ cf Wt[512];
    __shared__ cf W7[896];          // [t8][k-1] = w(8*t8)^k
    int tid = threadIdx.x;
    int blk = blockIdx.x;
    int b   = blk >> 8;
    int dp  = blk & 255;
    unsigned short* col0 = xT + ((size_t)(b * DDIM + 2 * dp)) * NSEQ;
    unsigned short* col1 = col0 + NSEQ;

    // ---- build tables ----
    {
        float sn, cs;
        __sincosf(-7.66990393942820625e-04f * (float)tid, &sn, &cs);  // -2pi t/8192
        Wt[tid] = {cs, sn};
        int e = tid;
        int t8 = e / 7, k = e - t8 * 7 + 1;
        __sincosf(-6.13592315154256492e-03f * (float)(t8 * k), &sn, &cs); // -pi/512*t8*k
        W7[e] = {cs, sn};
        if (tid < 384) {
            e = tid + 512;
            t8 = e / 7; k = e - t8 * 7 + 1;
            __sincosf(-6.13592315154256492e-03f * (float)(t8 * k), &sn, &cs);
            W7[e] = {cs, sn};
        }
    }
    __syncthreads();

    const cf KF = {0.92387953251128674f, -0.38268343236508977f};  // w(512)=e^{-i pi/8}

    // ---- fused load + first forward stage (lm=10, half-zero) ----
#pragma unroll
    for (int q = 0; q < 2; ++q) {
        int j = q * 512 + tid;
        cf a0 = {bf2f(col0[j]),        bf2f(col1[j])};
        cf a1 = {bf2f(col0[j + 1024]), bf2f(col1[j + 1024])};
        cf a2 = {bf2f(col0[j + 2048]), bf2f(col1[j + 2048])};
        cf a3 = {bf2f(col0[j + 3072]), bf2f(col1[j + 3072])};
        cf a[8];
        dft8_half<-1>(a0, a1, a2, a3, a);
        cf w1 = Wt[tid];
        if (q == 1) w1 = cmul(w1, KF);       // compile-time branch per q
        cf w[8];
        twpow(w1, w);
#pragma unroll
        for (int k = 1; k < 8; ++k) a[k] = cmul(a[k], w[k]);
#pragma unroll
        for (int r = 0; r < 8; ++r) Z[PADI(j + (r << 10))] = a[r];
    }
    __syncthreads();

    r8_stage_tab<-1, 7, 7>(Z, W7, tid);   __syncthreads();
    r8_stage_tab<-1, 4, 56>(Z, W7, tid);  __syncthreads();

    // ---- merged: fwd lm=1 + R2 diag(V) R2 + inv lm=1 (twiddles folded) ----
#pragma unroll
    for (int q = 0; q < 2; ++q) {
        const int idx = q * 512 + tid;
        const int g  = idx >> 1;
        const int jj = idx & 1;
        const int base = g * 16 + jj;
        cf a[8];
#pragma unroll
        for (int r = 0; r < 8; ++r) a[r] = Z[PADI(base + 2 * r)];
        dft8<-1>(a);
#pragma unroll
        for (int r = 0; r < 8; ++r) {
            cf own = a[r];
            cf oth;
            oth.x = __shfl_xor(own.x, 1);
            oth.y = __shfl_xor(own.y, 1);
            float4 v = Vt4[base + 2 * r];
            a[r] = cadd(cmul({v.x, v.y}, own), cmul({v.z, v.w}, oth));
        }
        dft8<1>(a);
#pragma unroll
        for (int r = 0; r < 8; ++r) Z[PADI(base + 2 * r)] = a[r];
    }
    __syncthreads();

    r8_stage_tab<1, 4, 56>(Z, W7, tid);   __syncthreads();
    r8_stage_tab<1, 7, 7>(Z, W7, tid);    __syncthreads();

    // ---- fused last inverse stage (lm=10) + store (only idx < 4096) ----
#pragma unroll
    for (int q = 0; q < 2; ++q) {
        int j = q * 512 + tid;
        cf a[8];
#pragma unroll
        for (int r = 0; r < 8; ++r) a[r] = Z[PADI(j + (r << 10))];
        cf w1 = Wt[tid];
        if (q == 1) w1 = cmul(w1, KF);
        w1.y = -w1.y;                       // conjugate for inverse
        cf w[8];
        twpow(w1, w);
#pragma unroll
        for (int k = 1; k < 8; ++k) a[k] = cmul(a[k], w[k]);
        dft8<1>(a);
#pragma unroll
        for (int r = 0; r < 4; ++r) {
            col0[j + (r << 10)] = f2bf(a[r].x);
            col1[j + (r << 10)] = f2bf(a[r].y);
        }
    }
}

// ---------------------------------------------------------------------------
// Kernel 3: un-transpose  out[b][j][d] = f32(outT[b][d][j]).  grid (64,8,8).
// ---------------------------------------------------------------------------
__global__ void untranspose(const unsigned short* __restrict__ oT,
                            float* __restrict__ out) {
    __shared__ unsigned short tl[64][65];
    int j0 = blockIdx.x * 64, d0 = blockIdx.y * 64, b = blockIdx.z;
    const unsigned short* src = oT + (size_t)b * DDIM * NSEQ;
#pragma unroll
    for (int e = 0; e < 16; ++e) {
        int idx = e * 256 + threadIdx.x;
        int r = idx >> 6, c = idx & 63;
        tl[r][c] = src[(size_t)(d0 + r) * NSEQ + j0 + c];
    }
    __syncthreads();
    float* dst = out + ((size_t)b * NSEQ + j0) * DDIM + d0;
#pragma unroll
    for (int e = 0; e < 16; ++e) {
        int idx = e * 256 + threadIdx.x;
        int r = idx >> 6, c = idx & 63;
        dst[(size_t)r * DDIM + c] = bf2f(tl[c][r]);
    }
}

// ---------------------------------------------------------------------------
extern "C" void kernel_launch(void* const* d_in, const int* in_sizes, int n_in,
                              void* d_out, int out_size, void* d_ws, size_t ws_size,
                              hipStream_t stream) {
    const float* x    = (const float*)d_in[0];
    const float* pos  = (const float*)d_in[1];
    const float* zero = (const float*)d_in[2];
    const float* neg  = (const float*)d_in[3];
    float* out = (float*)d_out;

    unsigned short* xT = (unsigned short*)d_ws;                       // 32 MiB
    float4* Vt = (float4*)((char*)d_ws + (size_t)32 * 1024 * 1024);   // 128 KiB

    prep<<<dim3(4097), 512, 0, stream>>>(x, pos, zero, neg, xT, Vt);
    fft_conv<<<dim3(NB * 256), 512, 0, stream>>>(xT, Vt);
    untranspose<<<dim3(64, 8, 8), 256, 0, stream>>>(xT, out);
}